// Round 4
// baseline (38755.533 us; speedup 1.0000x reference)
//
#include <hip/hip_runtime.h>
#include <stdint.h>

#define DEV static __device__ __forceinline__

typedef float f32x4 __attribute__((ext_vector_type(4)));
typedef unsigned int u32x4 __attribute__((ext_vector_type(4)));
typedef short s16x8 __attribute__((ext_vector_type(8)));   // 8 bf16 in 4 VGPRs

DEV unsigned short f2bf(float f) {
    union { float f; unsigned int u; } v; v.f = f;
    unsigned int u = v.u;
    return (unsigned short)((u + 0x7FFFu + ((u >> 16) & 1u)) >> 16);
}
DEV float bf2f(unsigned short u) {
    union { unsigned int i; float f; } v; v.i = ((unsigned int)u) << 16;
    return v.f;
}
DEV float sigm(float x) { return __fdividef(1.0f, 1.0f + __expf(-x)); }
DEV float tanh_(float x) { return 1.0f - __fdividef(2.0f, __expf(2.0f * x) + 1.0f); }

DEV f32x4 mfma_bf16(s16x8 a, s16x8 b, f32x4 c) {
    return __builtin_amdgcn_mfma_f32_16x16x32_bf16(a, b, c, 0, 0, 0);
}

// ---------------- packing pre-passes ----------------

// fp32 -> bf16 hi + lo residual
__global__ __launch_bounds__(256) void split_bf16(const float* __restrict__ src,
    unsigned short* __restrict__ hi, unsigned short* __restrict__ lo, int n) {
    int o = blockIdx.x * 256 + threadIdx.x;
    if (o >= n) return;
    float v = src[o];
    unsigned short h = f2bf(v);
    hi[o] = h;
    lo[o] = f2bf(v - bf2f(h));
}
__global__ __launch_bounds__(256) void cvt_bf16(const float* __restrict__ src, unsigned short* __restrict__ dst, int n) {
    int o = blockIdx.x * 256 + threadIdx.x;
    if (o < n) dst[o] = f2bf(src[o]);
}
// W_ih_l0 [1024][16] -> [1024][32] bf16 zero-padded K
__global__ __launch_bounds__(256) void pad_wih(const float* __restrict__ src, unsigned short* __restrict__ dst) {
    int o = blockIdx.x * 256 + threadIdx.x;   // 32768
    int k = o & 31, r = o >> 5;
    dst[o] = (k < 16) ? f2bf(src[r * 16 + k]) : (unsigned short)0;
}
// x [512][512][16] f32 -> [512][512][32] bf16 zero-padded K
__global__ __launch_bounds__(256) void pad_x(const float* __restrict__ src, unsigned short* __restrict__ dst) {
    int o = blockIdx.x * 256 + threadIdx.x;   // 8388608
    int k = o & 31;
    int t = (o >> 5) & 511;
    int b = o >> 14;
    dst[o] = (k < 16) ? f2bf(src[((size_t)b * 512 + t) * 16 + k]) : (unsigned short)0;
}
// fc_w [64][512] -> [512][64]
__global__ __launch_bounds__(256) void transpose_fcw(const float* __restrict__ src, float* __restrict__ dst) {
    int o = blockIdx.x * 256 + threadIdx.x;   // 32768
    int j = o >> 6, l = o & 63;
    dst[o] = src[l * 512 + j];
}

// LDS swizzled h tile: 2 parts (hi/lo) x 64 rows x 256 bf16; 16B chunks XOR-swizzled
DEV int hs_off(int part, int row, int chunk) {
    return part * 16384 + row * 256 + ((chunk ^ (row & 7)) << 3);   // ushort units
}

// ---------------- layer 0 step (both dirs) ----------------
// grid = 2 * nbt * 4; WG: 64 batch rows x 64 hidden cols (4 waves of 16 cols x 4 gates)
// h stored [dir][part hi/lo][b][256] bf16, ping-pong. c: [dir][b][256] f32.
__global__ __launch_bounds__(256) void l0_step(
    int s, int b0, int Bc, int btb,
    const unsigned short* __restrict__ xbf,
    const unsigned short* __restrict__ WihF, const unsigned short* __restrict__ WihB,
    const unsigned short* __restrict__ WhiF, const unsigned short* __restrict__ WhiB,
    const unsigned short* __restrict__ WloF, const unsigned short* __restrict__ WloB,
    const float* __restrict__ bF, const float* __restrict__ bB,
    const unsigned short* __restrict__ hR, unsigned short* __restrict__ hW,
    float* __restrict__ cst, unsigned short* __restrict__ out0)
{
    __shared__ unsigned short h_s[2 * 64 * 256];   // 64KB, XOR-swizzled
    int tid = threadIdx.x;
    int wave = tid >> 6, lane = tid & 63;
    int wg = blockIdx.x;
    int jblk = wg & 3;
    int bt = (wg >> 2) & ((1 << btb) - 1);
    int dir = wg >> (2 + btb);
    int r0 = bt * 64;
    int t = dir ? 511 - s : s;
    const unsigned short* Wih = dir ? WihB : WihF;
    const unsigned short* Whi = dir ? WhiB : WhiF;
    const unsigned short* Wlo = dir ? WloB : WloF;
    const float* bias = dir ? bB : bF;

    // stage h hi+lo (each 64 rows x 512B)
    #pragma unroll
    for (int part = 0; part < 2; ++part) {
        const unsigned short* hp = hR + (size_t)(dir * 2 + part) * (Bc * 256) + r0 * 256;
        #pragma unroll
        for (int it = 0; it < 8; ++it) {
            int idx = it * 256 + tid;
            int row = idx >> 5, seg = idx & 31;
            *(u32x4*)(h_s + hs_off(part, row, seg)) = *(const u32x4*)(hp + row * 256 + seg * 8);
        }
    }

    int l15 = lane & 15, q = lane >> 4;
    int j0w = jblk * 64 + wave * 16;

    f32x4 acc[4][4];
    #pragma unroll
    for (int g = 0; g < 4; ++g) {
        float bv = bias[g * 256 + j0w + l15];
        f32x4 v = { bv, bv, bv, bv };
        acc[0][g] = v; acc[1][g] = v; acc[2][g] = v; acc[3][g] = v;
    }

    // input term: K=32 padded
    {
        s16x8 ax[4], bx[4];
        #pragma unroll
        for (int i = 0; i < 4; ++i)
            ax[i] = *(const s16x8*)(xbf + ((size_t)(b0 + r0 + 16 * i + l15) * 512 + t) * 32 + q * 8);
        #pragma unroll
        for (int g = 0; g < 4; ++g)
            bx[g] = *(const s16x8*)(Wih + (g * 256 + j0w + l15) * 32 + q * 8);
        #pragma unroll
        for (int i = 0; i < 4; ++i)
            #pragma unroll
            for (int g = 0; g < 4; ++g)
                acc[i][g] = mfma_bf16(ax[i], bx[g], acc[i][g]);
    }
    __syncthreads();

    // recurrent: acc += h_hi*W_hi + h_lo*W_hi + h_hi*W_lo
    for (int k0 = 0; k0 < 256; k0 += 32) {
        int cb = (k0 >> 3) + q;
        s16x8 ah[4], al[4], bh[4], bl[4];
        #pragma unroll
        for (int i = 0; i < 4; ++i) {
            ah[i] = *(const s16x8*)(h_s + hs_off(0, 16 * i + l15, cb));
            al[i] = *(const s16x8*)(h_s + hs_off(1, 16 * i + l15, cb));
        }
        #pragma unroll
        for (int g = 0; g < 4; ++g) {
            size_t wo = (size_t)(g * 256 + j0w + l15) * 256 + k0 + q * 8;
            bh[g] = *(const s16x8*)(Whi + wo);
            bl[g] = *(const s16x8*)(Wlo + wo);
        }
        #pragma unroll
        for (int i = 0; i < 4; ++i)
            #pragma unroll
            for (int g = 0; g < 4; ++g) {
                acc[i][g] = mfma_bf16(ah[i], bh[g], acc[i][g]);
                acc[i][g] = mfma_bf16(al[i], bh[g], acc[i][g]);
                acc[i][g] = mfma_bf16(ah[i], bl[g], acc[i][g]);
            }
    }

    // epilogue: C/D row = q*4+e within tile, col = l15
    #pragma unroll
    for (int i = 0; i < 4; ++i) {
        #pragma unroll
        for (int e = 0; e < 4; ++e) {
            int r = r0 + 16 * i + q * 4 + e;
            int j = j0w + l15;
            float gi = acc[i][0][e], gf = acc[i][1][e], gg = acc[i][2][e], go = acc[i][3][e];
            float* cp = cst + (size_t)dir * (Bc * 256) + r * 256 + j;
            float cn = sigm(gf) * (*cp) + sigm(gi) * tanh_(gg);
            *cp = cn;
            float h = sigm(go) * tanh_(cn);
            unsigned short hhi = f2bf(h);
            unsigned short hlo = f2bf(h - bf2f(hhi));
            hW[(size_t)(dir * 2 + 0) * (Bc * 256) + r * 256 + j] = hhi;
            hW[(size_t)(dir * 2 + 1) * (Bc * 256) + r * 256 + j] = hlo;
            out0[((size_t)t * Bc + r) * 512 + dir * 256 + j] = hhi;
        }
    }
}

// ---------------- layer 1 step ----------------
__global__ __launch_bounds__(256) void l1_step(
    int s, int Bc, int btb,
    const float* __restrict__ Gf, const float* __restrict__ Gb,
    const unsigned short* __restrict__ WhiF, const unsigned short* __restrict__ WhiB,
    const unsigned short* __restrict__ WloF, const unsigned short* __restrict__ WloB,
    const float* __restrict__ bF, const float* __restrict__ bB,
    const unsigned short* __restrict__ hR, unsigned short* __restrict__ hW,
    float* __restrict__ cst)
{
    __shared__ unsigned short h_s[2 * 64 * 256];
    int tid = threadIdx.x;
    int wave = tid >> 6, lane = tid & 63;
    int wg = blockIdx.x;
    int jblk = wg & 3;
    int bt = (wg >> 2) & ((1 << btb) - 1);
    int dir = wg >> (2 + btb);
    int r0 = bt * 64;
    const unsigned short* Whi = dir ? WhiB : WhiF;
    const unsigned short* Wlo = dir ? WloB : WloF;
    const float* bias = dir ? bB : bF;
    int slot = dir ? (7 - (s & 7)) : (s & 7);

    #pragma unroll
    for (int part = 0; part < 2; ++part) {
        const unsigned short* hp = hR + (size_t)(dir * 2 + part) * (Bc * 256) + r0 * 256;
        #pragma unroll
        for (int it = 0; it < 8; ++it) {
            int idx = it * 256 + tid;
            int row = idx >> 5, seg = idx & 31;
            *(u32x4*)(h_s + hs_off(part, row, seg)) = *(const u32x4*)(hp + row * 256 + seg * 8);
        }
    }

    int l15 = lane & 15, q = lane >> 4;
    int j0w = jblk * 64 + wave * 16;

    // acc init: G blob (raw MFMA fragments) + bias
    f32x4 acc[4][4];
    {
        const f32x4* Gv = (const f32x4*)(dir ? Gb : Gf);
        int mtbase = ((slot * Bc) >> 4) + (r0 >> 4);
        #pragma unroll
        for (int m = 0; m < 4; ++m)
            #pragma unroll
            for (int g = 0; g < 4; ++g) {
                f32x4 v = Gv[((size_t)(mtbase + m) * 64 + (g * 16 + (j0w >> 4))) * 64 + lane];
                float bv = bias[g * 256 + j0w + l15];
                f32x4 bb = { bv, bv, bv, bv };
                acc[m][g] = v + bb;
            }
    }
    __syncthreads();

    for (int k0 = 0; k0 < 256; k0 += 32) {
        int cb = (k0 >> 3) + q;
        s16x8 ah[4], al[4], bh[4], bl[4];
        #pragma unroll
        for (int i = 0; i < 4; ++i) {
            ah[i] = *(const s16x8*)(h_s + hs_off(0, 16 * i + l15, cb));
            al[i] = *(const s16x8*)(h_s + hs_off(1, 16 * i + l15, cb));
        }
        #pragma unroll
        for (int g = 0; g < 4; ++g) {
            size_t wo = (size_t)(g * 256 + j0w + l15) * 256 + k0 + q * 8;
            bh[g] = *(const s16x8*)(Whi + wo);
            bl[g] = *(const s16x8*)(Wlo + wo);
        }
        #pragma unroll
        for (int i = 0; i < 4; ++i)
            #pragma unroll
            for (int g = 0; g < 4; ++g) {
                acc[i][g] = mfma_bf16(ah[i], bh[g], acc[i][g]);
                acc[i][g] = mfma_bf16(al[i], bh[g], acc[i][g]);
                acc[i][g] = mfma_bf16(ah[i], bl[g], acc[i][g]);
            }
    }

    #pragma unroll
    for (int i = 0; i < 4; ++i) {
        #pragma unroll
        for (int e = 0; e < 4; ++e) {
            int r = r0 + 16 * i + q * 4 + e;
            int j = j0w + l15;
            float gi = acc[i][0][e], gf = acc[i][1][e], gg = acc[i][2][e], go = acc[i][3][e];
            float* cp = cst + (size_t)dir * (Bc * 256) + r * 256 + j;
            float cn = sigm(gf) * (*cp) + sigm(gi) * tanh_(gg);
            *cp = cn;
            float h = sigm(go) * tanh_(cn);
            unsigned short hhi = f2bf(h);
            unsigned short hlo = f2bf(h - bf2f(hhi));
            hW[(size_t)(dir * 2 + 0) * (Bc * 256) + r * 256 + j] = hhi;
            hW[(size_t)(dir * 2 + 1) * (Bc * 256) + r * 256 + j] = hlo;
        }
    }
}

// ---------------- layer-1 input GEMM -> fragment blob ----------------
// A [8*Bc rows][512] bf16, W [1024][512] bf16; G blob [mt][nt 64][lane 64][4] f32
__global__ __launch_bounds__(256) void g1_gemm(
    int mt_bits,
    const unsigned short* __restrict__ Af, const unsigned short* __restrict__ Ab,
    const unsigned short* __restrict__ Wf, const unsigned short* __restrict__ Wb,
    float* __restrict__ Gf, float* __restrict__ Gb)
{
    __shared__ unsigned short As[128 * 40];
    __shared__ unsigned short Bs[128 * 40];
    int gid = blockIdx.x;
    int dir = gid >> (3 + mt_bits);
    int rem = gid & ((1 << (3 + mt_bits)) - 1);
    int n0 = (rem >> mt_bits) << 7;
    int m0 = (rem & ((1 << mt_bits) - 1)) << 7;
    const unsigned short* A = dir ? Ab : Af;
    const unsigned short* W = dir ? Wb : Wf;
    float* G = dir ? Gb : Gf;
    int tid = threadIdx.x;
    int lane = tid & 63, wave = tid >> 6;
    int wm = (wave >> 1) * 64, wn = (wave & 1) * 64;
    int l15 = lane & 15, lq = lane >> 4;

    f32x4 acc[4][4];
    f32x4 z = { 0.f, 0.f, 0.f, 0.f };
    #pragma unroll
    for (int i = 0; i < 4; ++i)
        #pragma unroll
        for (int j = 0; j < 4; ++j) acc[i][j] = z;

    for (int k0 = 0; k0 < 512; k0 += 32) {
        #pragma unroll
        for (int h = 0; h < 2; ++h) {
            int sseg = h * 256 + tid;
            int row = sseg >> 2, qq = sseg & 3;
            *(u32x4*)(As + row * 40 + qq * 8) = *(const u32x4*)(A + (size_t)(m0 + row) * 512 + k0 + qq * 8);
            *(u32x4*)(Bs + row * 40 + qq * 8) = *(const u32x4*)(W + (size_t)(n0 + row) * 512 + k0 + qq * 8);
        }
        __syncthreads();
        s16x8 af[4], bf[4];
        #pragma unroll
        for (int i = 0; i < 4; ++i) {
            af[i] = *(const s16x8*)(As + (wm + i * 16 + l15) * 40 + lq * 8);
            bf[i] = *(const s16x8*)(Bs + (wn + i * 16 + l15) * 40 + lq * 8);
        }
        #pragma unroll
        for (int i = 0; i < 4; ++i)
            #pragma unroll
            for (int j = 0; j < 4; ++j)
                acc[i][j] = mfma_bf16(af[i], bf[j], acc[i][j]);
        __syncthreads();
    }
    int mtb = (m0 + wm) >> 4, ntb = (n0 + wn) >> 4;
    f32x4* Gv = (f32x4*)G;
    #pragma unroll
    for (int i = 0; i < 4; ++i)
        #pragma unroll
        for (int j = 0; j < 4; ++j)
            Gv[((size_t)(mtb + i) * 64 + (ntb + j)) * 64 + lane] = acc[i][j];
}

// ---------------- final FC ----------------
__global__ __launch_bounds__(64) void fc_kernel(
    const unsigned short* __restrict__ h /* [2dir][2part][Bc][256] */,
    const float* __restrict__ fcwT, const float* __restrict__ fcb,
    float* __restrict__ out, int b0, int Bc)
{
    __shared__ float hc[512];
    int b = blockIdx.x, l = threadIdx.x;
    #pragma unroll
    for (int it = 0; it < 8; ++it) {
        int jj = it * 64 + l;            // 0..511
        int d = jj >> 8, j = jj & 255;
        size_t hi_o = ((size_t)(d * 2 + 0) * Bc + b) * 256 + j;
        size_t lo_o = ((size_t)(d * 2 + 1) * Bc + b) * 256 + j;
        hc[jj] = bf2f(h[hi_o]) + bf2f(h[lo_o]);
    }
    __syncthreads();
    float acc = fcb[l];
    for (int j = 0; j < 512; ++j) acc += hc[j] * fcwT[j * 64 + l];
    out[(b0 + b) * 64 + l] = acc;
}

// ---------------- host ----------------
extern "C" void kernel_launch(void* const* d_in, const int* in_sizes, int n_in,
                              void* d_out, int out_size, void* d_ws, size_t ws_size,
                              hipStream_t stream)
{
    const float* x     = (const float*)d_in[0];
    const float* wih0f = (const float*)d_in[1];
    const float* whh0f = (const float*)d_in[2];
    const float* b0f   = (const float*)d_in[3];
    const float* wih0b = (const float*)d_in[4];
    const float* whh0b = (const float*)d_in[5];
    const float* b0b   = (const float*)d_in[6];
    const float* wih1f = (const float*)d_in[7];
    const float* whh1f = (const float*)d_in[8];
    const float* b1f   = (const float*)d_in[9];
    const float* wih1b = (const float*)d_in[10];
    const float* whh1b = (const float*)d_in[11];
    const float* b1b   = (const float*)d_in[12];
    const float* fcw   = (const float*)d_in[13];
    const float* fcb   = (const float*)d_in[14];
    float* out = (float*)d_out;
    (void)in_sizes; (void)n_in; (void)out_size;

    // per-row: out0 512*512*2 + G 2*8*1024*4 + h 2*2*2*256*2 + c 2*256*4
    const size_t per_row = 524288 + 65536 + 4096 + 2048;
    const size_t fixed   = 33554432;   // xbf 16MB + weights ~5MB + margin
    int Bc = 512;
    while (Bc > 64 && fixed + per_row * (size_t)Bc > ws_size) Bc >>= 1;
    const int nb = 512 / Bc;
    const int nbt = Bc / 64;
    const int btb = 31 - __builtin_clz((unsigned)nbt);
    const int mt_bits = (31 - __builtin_clz((unsigned)Bc)) - 4;
    const int gemm_grid = 2 << (3 + mt_bits);
    const int step_grid = 8 * nbt;

    char* p = (char*)d_ws;
    auto alloc = [&](size_t bytes) -> void* {
        void* r = (void*)p;
        p += (bytes + 255) & ~(size_t)255;
        return r;
    };
    unsigned short* Whi0f = (unsigned short*)alloc(262144 * 2);
    unsigned short* Wlo0f = (unsigned short*)alloc(262144 * 2);
    unsigned short* Whi0b = (unsigned short*)alloc(262144 * 2);
    unsigned short* Wlo0b = (unsigned short*)alloc(262144 * 2);
    unsigned short* Whi1f = (unsigned short*)alloc(262144 * 2);
    unsigned short* Wlo1f = (unsigned short*)alloc(262144 * 2);
    unsigned short* Whi1b = (unsigned short*)alloc(262144 * 2);
    unsigned short* Wlo1b = (unsigned short*)alloc(262144 * 2);
    unsigned short* WihPf = (unsigned short*)alloc(1024 * 32 * 2);
    unsigned short* WihPb = (unsigned short*)alloc(1024 * 32 * 2);
    unsigned short* xbf   = (unsigned short*)alloc((size_t)512 * 512 * 32 * 2);
    unsigned short* W1bf_f = (unsigned short*)alloc(1024 * 512 * 2);
    unsigned short* W1bf_b = (unsigned short*)alloc(1024 * 512 * 2);
    float* fcwT = (float*)alloc(512 * 64 * 4);
    unsigned short* hbuf = (unsigned short*)alloc((size_t)2 * 2 * 2 * Bc * 256 * 2); // [pp][dir][part][b][k]
    float* cbuf = (float*)alloc((size_t)2 * Bc * 256 * 4);
    unsigned short* out0 = (unsigned short*)alloc((size_t)512 * Bc * 512 * 2);
    float* G1f = (float*)alloc((size_t)8 * Bc * 1024 * 4);
    float* G1b = (float*)alloc((size_t)8 * Bc * 1024 * 4);

    split_bf16<<<1024, 256, 0, stream>>>(whh0f, Whi0f, Wlo0f, 262144);
    split_bf16<<<1024, 256, 0, stream>>>(whh0b, Whi0b, Wlo0b, 262144);
    split_bf16<<<1024, 256, 0, stream>>>(whh1f, Whi1f, Wlo1f, 262144);
    split_bf16<<<1024, 256, 0, stream>>>(whh1b, Whi1b, Wlo1b, 262144);
    pad_wih<<<128, 256, 0, stream>>>(wih0f, WihPf);
    pad_wih<<<128, 256, 0, stream>>>(wih0b, WihPb);
    pad_x<<<32768, 256, 0, stream>>>(x, xbf);
    cvt_bf16<<<2048, 256, 0, stream>>>(wih1f, W1bf_f, 1024 * 512);
    cvt_bf16<<<2048, 256, 0, stream>>>(wih1b, W1bf_b, 1024 * 512);
    transpose_fcw<<<128, 256, 0, stream>>>(fcw, fcwT);

    const size_t hslot = (size_t)2 * 2 * Bc * 256;   // ushorts per pingpong slot

    for (int bchunk = 0; bchunk < nb; ++bchunk) {
        int b0 = bchunk * Bc;

        // ---- layer 0 ----
        hipMemsetAsync(hbuf, 0, hslot * 2 * 2, stream);
        hipMemsetAsync(cbuf, 0, (size_t)2 * Bc * 256 * 4, stream);
        for (int s = 0; s < 512; ++s) {
            const unsigned short* hRp = hbuf + (size_t)(s & 1) * hslot;
            unsigned short* hWp = hbuf + (size_t)((s + 1) & 1) * hslot;
            l0_step<<<step_grid, 256, 0, stream>>>(s, b0, Bc, btb, xbf,
                WihPf, WihPb, Whi0f, Whi0b, Wlo0f, Wlo0b, b0f, b0b,
                hRp, hWp, cbuf, out0);
        }

        // ---- layer 1: 8-step chunks ----
        hipMemsetAsync(hbuf, 0, hslot * 2 * 2, stream);
        hipMemsetAsync(cbuf, 0, (size_t)2 * Bc * 256 * 4, stream);
        for (int c = 0; c < 64; ++c) {
            const unsigned short* Afp = out0 + (size_t)(c * 8) * Bc * 512;
            const unsigned short* Abp = out0 + (size_t)(504 - 8 * c) * Bc * 512;
            g1_gemm<<<gemm_grid, 256, 0, stream>>>(mt_bits, Afp, Abp, W1bf_f, W1bf_b, G1f, G1b);
            for (int i = 0; i < 8; ++i) {
                int s = c * 8 + i;
                const unsigned short* hRp = hbuf + (size_t)(s & 1) * hslot;
                unsigned short* hWp = hbuf + (size_t)((s + 1) & 1) * hslot;
                l1_step<<<step_grid, 256, 0, stream>>>(s, Bc, btb, G1f, G1b,
                    Whi1f, Whi1b, Wlo1f, Wlo1b, b1f, b1b, hRp, hWp, cbuf);
            }
        }

        fc_kernel<<<Bc, 64, 0, stream>>>(hbuf, fcwT, fcb, out, b0, Bc);
    }
}